// Round 1
// baseline (1628.278 us; speedup 1.0000x reference)
//
#include <hip/hip_runtime.h>
#include <hip/hip_bf16.h>
#include <stdint.h>

// RPGNN: random-permutation GIN (NUM_PERM=1), N=100k, E=600k, G=2000
// D=128, concat one-hot(rank%10) -> 138 (padded to 144), H=O=256.

#define D_IN   128
#define KRAW   138
#define KPAD   144
#define HDIM   256
#define NGRAPH 2000

// ---------------- threefry2x32 (bit-exact JAX replica) ----------------
__device__ __forceinline__ unsigned rotl32(unsigned x, int r) {
  return (x << r) | (x >> (32 - r));
}

__device__ __forceinline__ void threefry2x32(unsigned k0, unsigned k1,
                                             unsigned x0, unsigned x1,
                                             unsigned& o0, unsigned& o1) {
  unsigned ks2 = k0 ^ k1 ^ 0x1BD11BDAu;
  unsigned ks[3] = {k0, k1, ks2};
  x0 += ks[0]; x1 += ks[1];
  const int rotA[4] = {13, 15, 26, 6};
  const int rotB[4] = {17, 29, 16, 24};
#pragma unroll
  for (int i = 0; i < 5; ++i) {
    const int* rot = (i & 1) ? rotB : rotA;
#pragma unroll
    for (int j = 0; j < 4; ++j) {
      x0 += x1; x1 = rotl32(x1, rot[j]); x1 ^= x0;
    }
    x0 += ks[(i + 1) % 3];
    x1 += ks[(i + 2) % 3] + (unsigned)(i + 1);
  }
  o0 = x0; o1 = x1;
}

// r[i] = uniform from fold_in(key(42), 0); also segment starts + counts
__global__ void k_prep(const int* __restrict__ bids, float* __restrict__ r,
                       int* __restrict__ start, int* __restrict__ cnt, int N) {
  int i = blockIdx.x * blockDim.x + threadIdx.x;
  if (i >= N) return;
  int half = N >> 1;
  if (i < half) {
    unsigned fk0, fk1;
    threefry2x32(0u, 42u, 0u, 0u, fk0, fk1);          // fold_in(key(42), 0)
    unsigned b0, b1v;
    threefry2x32(fk0, fk1, (unsigned)i, (unsigned)(i + half), b0, b1v);
    r[i]        = __uint_as_float((b0  >> 9) | 0x3f800000u) - 1.0f;
    r[i + half] = __uint_as_float((b1v >> 9) | 0x3f800000u) - 1.0f;
  }
  int g = bids[i];
  if (i == 0 || bids[i - 1] != g) start[g] = i;
  atomicAdd(&cnt[g], 1);
}

// rank within graph under key = float(g)+r, stable tie-break on index
__global__ void k_rank(const float* __restrict__ r, const int* __restrict__ start,
                       const int* __restrict__ cnt, int* __restrict__ ids) {
  int g = blockIdx.x;
  int st = start[g], n = cnt[g];
  if (n <= 0) return;
  float gf = (float)g;
  for (int t = threadIdx.x; t < n; t += blockDim.x) {
    int v = st + t;
    float kv = gf + r[v];
    int c = 0;
    for (int u0 = 0; u0 < n; ++u0) {
      int u = st + u0;
      float ku = gf + r[u];
      c += (int)((ku < kv) | ((ku == kv) & (u < v)));
    }
    ids[v] = c % 10;
  }
}

// padded W1: [144][256], zero rows 138..143
__global__ void k_wp(const float* __restrict__ W1, float* __restrict__ Wp) {
  int idx = blockIdx.x * 256 + threadIdx.x;  // 144*256
  int k = idx >> 8, n = idx & 255;
  Wp[idx] = (k < KRAW) ? W1[k * 256 + n] : 0.0f;
}

// agg1[v] = concat(x[v], onehot(ids[v]), 0pad)
__global__ void k_init1(const float* __restrict__ x, const int* __restrict__ ids,
                        float* __restrict__ agg1) {
  int v = blockIdx.x;
  int c = threadIdx.x;
  if (c >= KPAD) return;
  float val;
  if (c < D_IN)      val = x[(size_t)v * D_IN + c];
  else if (c < KRAW) val = (ids[v] == c - D_IN) ? 1.0f : 0.0f;
  else               val = 0.0f;
  agg1[(size_t)v * KPAD + c] = val;
}

// layer-1 message: agg1[dst] += concat(x[src], onehot(ids[src]))
__global__ void k_msg1(const float* __restrict__ x, const int* __restrict__ ids,
                       const int* __restrict__ src, const int* __restrict__ dst,
                       float* __restrict__ agg1, int E) {
  int w = (int)((blockIdx.x * (size_t)blockDim.x + threadIdx.x) >> 6);
  int lane = threadIdx.x & 63;
  if (w >= E) return;
  int s = src[w], d = dst[w];
  const float* xs = x + (size_t)s * D_IN;
  float* ad = agg1 + (size_t)d * KPAD;
  atomicAdd(&ad[lane], xs[lane]);
  atomicAdd(&ad[64 + lane], xs[64 + lane]);
  if (lane == 0) atomicAdd(&ad[D_IN + ids[s]], 1.0f);
}

// layer-2 message: m2[dst] += h[src]
__global__ void k_msg2(const float* __restrict__ h, const int* __restrict__ src,
                       const int* __restrict__ dst, float* __restrict__ m2, int E) {
  int w = (int)((blockIdx.x * (size_t)blockDim.x + threadIdx.x) >> 6);
  int lane = threadIdx.x & 63;
  if (w >= E) return;
  int s = src[w], d = dst[w];
  const float* hs = h + (size_t)s * HDIM;
  float* md = m2 + (size_t)d * HDIM;
#pragma unroll
  for (int q = 0; q < 4; ++q) atomicAdd(&md[q * 64 + lane], hs[q * 64 + lane]);
}

// fp32 tiled GEMM: C[M][256] = act(A @ B + bias); A row-major lda=KP.
// SUMA: A-operand = A + A2 elementwise. FINAL: atomic pool into C[bids[m]].
template <int KP, int BK, bool SUMA, bool FINAL>
__global__ __launch_bounds__(256) void k_gemm(
    const float* __restrict__ A, const float* __restrict__ A2,
    const float* __restrict__ B, const float* __restrict__ bias,
    float* __restrict__ C, const int* __restrict__ bids, int M) {
  constexpr int BM = 64, BN = 64;
  constexpr int LDS_A = BM + 4;  // 68: keeps float4 alignment, 2-way banks
  constexpr int LDS_B = BN + 4;
  __shared__ float a_s[BK * LDS_A];
  __shared__ float b_s[BK * LDS_B];

  int tid = threadIdx.x;
  int tx = tid & 15, ty = tid >> 4;
  int m0 = blockIdx.x * BM;
  int n0 = blockIdx.y * BN;

  float acc[4][4] = {};

  for (int k0 = 0; k0 < KP; k0 += BK) {
    // A tile -> transposed a_s[k][m]
    constexpr int AF = BM * BK / 4;
    for (int i = tid; i < AF; i += 256) {
      int row = i / (BK / 4);
      int kq = i % (BK / 4);
      float4 v = make_float4(0.f, 0.f, 0.f, 0.f);
      int grow = m0 + row;
      if (grow < M) {
        const float* p = A + (size_t)grow * KP + k0 + kq * 4;
        v = *reinterpret_cast<const float4*>(p);
        if (SUMA) {
          const float* p2 = A2 + (size_t)grow * KP + k0 + kq * 4;
          float4 v2 = *reinterpret_cast<const float4*>(p2);
          v.x += v2.x; v.y += v2.y; v.z += v2.z; v.w += v2.w;
        }
      }
      a_s[(kq * 4 + 0) * LDS_A + row] = v.x;
      a_s[(kq * 4 + 1) * LDS_A + row] = v.y;
      a_s[(kq * 4 + 2) * LDS_A + row] = v.z;
      a_s[(kq * 4 + 3) * LDS_A + row] = v.w;
    }
    // B tile b_s[k][n]
    constexpr int BF = BK * BN / 4;
    for (int i = tid; i < BF; i += 256) {
      int k = i / (BN / 4);
      int nq = i % (BN / 4);
      float4 v = *reinterpret_cast<const float4*>(B + (size_t)(k0 + k) * HDIM + n0 + nq * 4);
      *reinterpret_cast<float4*>(&b_s[k * LDS_B + nq * 4]) = v;
    }
    __syncthreads();

#pragma unroll 8
    for (int k = 0; k < BK; ++k) {
      float4 a4 = *reinterpret_cast<const float4*>(&a_s[k * LDS_A + ty * 4]);
      float4 b4 = *reinterpret_cast<const float4*>(&b_s[k * LDS_B + tx * 4]);
      float av[4] = {a4.x, a4.y, a4.z, a4.w};
      float bv[4] = {b4.x, b4.y, b4.z, b4.w};
#pragma unroll
      for (int i = 0; i < 4; ++i)
#pragma unroll
        for (int j = 0; j < 4; ++j) acc[i][j] = fmaf(av[i], bv[j], acc[i][j]);
    }
    __syncthreads();
  }

#pragma unroll
  for (int i = 0; i < 4; ++i) {
    int rm = m0 + ty * 4 + i;
    if (rm >= M) continue;
    if (!FINAL) {
      float* cp = C + (size_t)rm * HDIM + n0 + tx * 4;
#pragma unroll
      for (int j = 0; j < 4; ++j) {
        float v = acc[i][j] + bias[n0 + tx * 4 + j];
        cp[j] = v > 0.f ? v : 0.f;
      }
    } else {
      int g = bids[rm];
      float* cp = C + (size_t)g * HDIM + n0 + tx * 4;
#pragma unroll
      for (int j = 0; j < 4; ++j) {
        float v = acc[i][j] + bias[n0 + tx * 4 + j];
        atomicAdd(&cp[j], v > 0.f ? v : 0.f);
      }
    }
  }
}

extern "C" void kernel_launch(void* const* d_in, const int* in_sizes, int n_in,
                              void* d_out, int out_size, void* d_ws, size_t ws_size,
                              hipStream_t stream) {
  const float* x    = (const float*)d_in[0];
  const int*   ei   = (const int*)d_in[1];
  const int*   bids = (const int*)d_in[2];
  const float* W1   = (const float*)d_in[3];
  const float* b1   = (const float*)d_in[4];
  const float* W2   = (const float*)d_in[5];
  const float* b2   = (const float*)d_in[6];
  float* out = (float*)d_out;

  const int N = in_sizes[2];
  const int E = in_sizes[1] / 2;
  const int* src = ei;
  const int* dst = ei + E;

  // workspace layout (256B aligned)
  char* ws = (char*)d_ws;
  size_t off = 0;
  auto alloc = [&](size_t bytes) {
    size_t o = off;
    off = (off + bytes + 255) & ~(size_t)255;
    return o;
  };
  float* r     = (float*)(ws + alloc((size_t)N * 4));
  int*   ids   = (int*)(ws + alloc((size_t)N * 4));
  int*   start = (int*)(ws + alloc((size_t)NGRAPH * 4));
  int*   cnt   = (int*)(ws + alloc((size_t)NGRAPH * 4));
  float* Wp    = (float*)(ws + alloc((size_t)KPAD * HDIM * 4));
  float* h     = (float*)(ws + alloc((size_t)N * HDIM * 4));
  // union region: agg1 (N*KPAD) early, m2 (N*HDIM) late
  float* uni   = (float*)(ws + alloc((size_t)N * HDIM * 4));
  float* agg1  = uni;
  float* m2    = uni;
  (void)ws_size;

  hipMemsetAsync(cnt, 0, (size_t)NGRAPH * 4, stream);
  hipMemsetAsync(out, 0, (size_t)out_size * 4, stream);

  k_prep<<<(N + 255) / 256, 256, 0, stream>>>(bids, r, start, cnt, N);
  k_wp<<<KPAD, 256, 0, stream>>>(W1, Wp);
  k_rank<<<NGRAPH, 64, 0, stream>>>(r, start, cnt, ids);
  k_init1<<<N, 192, 0, stream>>>(x, ids, agg1);
  k_msg1<<<(E + 3) / 4, 256, 0, stream>>>(x, ids, src, dst, agg1, E);

  dim3 gg1((N + 63) / 64, 4);
  k_gemm<KPAD, 48, false, false><<<gg1, 256, 0, stream>>>(agg1, nullptr, Wp, b1, h, nullptr, N);

  hipMemsetAsync(m2, 0, (size_t)N * HDIM * 4, stream);  // after gemm1 (overlays agg1)
  k_msg2<<<(E + 3) / 4, 256, 0, stream>>>(h, src, dst, m2, E);

  dim3 gg2((N + 63) / 64, 4);
  k_gemm<HDIM, 64, true, true><<<gg2, 256, 0, stream>>>(h, m2, W2, b2, out, bids, N);
}

// Round 2
// 573.572 us; speedup vs baseline: 2.8388x; 2.8388x over previous
//
#include <hip/hip_runtime.h>
#include <hip/hip_bf16.h>
#include <stdint.h>

// RPGNN: random-permutation GIN (NUM_PERM=1), N=100k, E=600k, G=2000
// Pipeline: threefry ranks -> CSR build -> gather-agg (no atomics) ->
// bf16 MFMA GEMM1 -> gather-agg2 -> bf16 MFMA GEMM2 with fused segment pooling.

#define D_IN   128
#define KRAW   138
#define K1P    160   // K of layer-1 GEMM, padded to multiple of 32
#define HDIM   256
#define NGRAPH 2000

typedef __bf16 bf16x8 __attribute__((ext_vector_type(8)));
typedef float  f32x4  __attribute__((ext_vector_type(4)));

__device__ __forceinline__ unsigned short f2b(float f) {
  __hip_bfloat16 h = __float2bfloat16(f);
  return __builtin_bit_cast(unsigned short, h);
}
__device__ __forceinline__ float b2f(unsigned short u) {
  return __uint_as_float(((unsigned)u) << 16);
}

// ---------------- threefry2x32 (bit-exact JAX replica) ----------------
__device__ __forceinline__ unsigned rotl32(unsigned x, int r) {
  return (x << r) | (x >> (32 - r));
}
__device__ __forceinline__ void threefry2x32(unsigned k0, unsigned k1,
                                             unsigned x0, unsigned x1,
                                             unsigned& o0, unsigned& o1) {
  unsigned ks2 = k0 ^ k1 ^ 0x1BD11BDAu;
  unsigned ks[3] = {k0, k1, ks2};
  x0 += ks[0]; x1 += ks[1];
  const int rotA[4] = {13, 15, 26, 6};
  const int rotB[4] = {17, 29, 16, 24};
#pragma unroll
  for (int i = 0; i < 5; ++i) {
    const int* rot = (i & 1) ? rotB : rotA;
#pragma unroll
    for (int j = 0; j < 4; ++j) {
      x0 += x1; x1 = rotl32(x1, rot[j]); x1 ^= x0;
    }
    x0 += ks[(i + 1) % 3];
    x1 += ks[(i + 2) % 3] + (unsigned)(i + 1);
  }
  o0 = x0; o1 = x1;
}

__global__ void k_prep(const int* __restrict__ bids, float* __restrict__ r,
                       int* __restrict__ start, int* __restrict__ cnt, int N) {
  int i = blockIdx.x * blockDim.x + threadIdx.x;
  if (i >= N) return;
  int half = N >> 1;
  if (i < half) {
    unsigned fk0, fk1;
    threefry2x32(0u, 42u, 0u, 0u, fk0, fk1);          // fold_in(key(42), 0)
    unsigned b0, b1v;
    threefry2x32(fk0, fk1, (unsigned)i, (unsigned)(i + half), b0, b1v);
    r[i]        = __uint_as_float((b0  >> 9) | 0x3f800000u) - 1.0f;
    r[i + half] = __uint_as_float((b1v >> 9) | 0x3f800000u) - 1.0f;
  }
  int g = bids[i];
  if (i == 0 || bids[i - 1] != g) start[g] = i;
  atomicAdd(&cnt[g], 1);
}

// rank within graph under key = float(g)+r (fp32, same rounding as XLA),
// stable tie-break on index; ids = rank % 10
__global__ void k_rank(const float* __restrict__ r, const int* __restrict__ start,
                       const int* __restrict__ cnt, int* __restrict__ ids) {
  int g = blockIdx.x;
  int st = start[g], n = cnt[g];
  if (n <= 0) return;
  float gf = (float)g;
  for (int t = threadIdx.x; t < n; t += blockDim.x) {
    int v = st + t;
    float kv = gf + r[v];
    int c = 0;
    for (int u0 = 0; u0 < n; ++u0) {
      int u = st + u0;
      float ku = gf + r[u];
      c += (int)((ku < kv) | ((ku == kv) & (u < v)));
    }
    ids[v] = c % 10;
  }
}

// ---------------- CSR build ----------------
__global__ void k_deg(const int* __restrict__ dst, int* __restrict__ deg, int E) {
  int e = blockIdx.x * 256 + threadIdx.x;
  if (e < E) atomicAdd(&deg[dst[e]], 1);
}

__global__ void k_scan1(const int* __restrict__ deg, int* __restrict__ rowptr,
                        int* __restrict__ bsum, int N) {
  __shared__ int buf[256];
  int tid = threadIdx.x;
  int i = blockIdx.x * 256 + tid;
  int v = (i < N) ? deg[i] : 0;
  buf[tid] = v;
  __syncthreads();
  for (int off = 1; off < 256; off <<= 1) {
    int t = (tid >= off) ? buf[tid - off] : 0;
    __syncthreads();
    buf[tid] += t;
    __syncthreads();
  }
  if (i < N) rowptr[i] = buf[tid] - v;   // local exclusive
  if (tid == 255) bsum[blockIdx.x] = buf[255];
}

__global__ void k_scan2(int* __restrict__ bsum, int nb) {
  __shared__ int buf[512];
  int tid = threadIdx.x;
  int v = (tid < nb) ? bsum[tid] : 0;
  buf[tid] = v;
  __syncthreads();
  for (int off = 1; off < 512; off <<= 1) {
    int t = (tid >= off) ? buf[tid - off] : 0;
    __syncthreads();
    buf[tid] += t;
    __syncthreads();
  }
  if (tid < nb) bsum[tid] = buf[tid] - v;  // exclusive
}

__global__ void k_scan3(int* __restrict__ rowptr, const int* __restrict__ bsum,
                        int N, int E) {
  int i = blockIdx.x * 256 + threadIdx.x;
  if (i < N) rowptr[i] += bsum[blockIdx.x];
  if (i == 0) rowptr[N] = E;
}

__global__ void k_scatter(const int* __restrict__ src, const int* __restrict__ dst,
                          const int* __restrict__ rowptr, int* __restrict__ fill,
                          int* __restrict__ csr, int E) {
  int e = blockIdx.x * 256 + threadIdx.x;
  if (e >= E) return;
  int d = dst[e];
  int pos = rowptr[d] + atomicAdd(&fill[d], 1);
  csr[pos] = src[e];
}

// ---------------- layer-1 aggregation (wave per node) ----------------
// agg1[v] = bf16(concat(x[v]+sum_u x[u], onehot(ids[v]) + hist(ids[u]), 0pad))
__global__ void k_agg1(const float* __restrict__ x, const int* __restrict__ ids,
                       const int* __restrict__ rowptr, const int* __restrict__ csr,
                       unsigned short* __restrict__ agg1, int N) {
  int v = blockIdx.x * 4 + (threadIdx.x >> 6);
  if (v >= N) return;
  int l = threadIdx.x & 63;
  float2 acc = reinterpret_cast<const float2*>(x + (size_t)v * D_IN)[l];
  int e0 = rowptr[v], e1 = rowptr[v + 1];
  for (int e = e0; e < e1; ++e) {
    int u = csr[e];
    float2 t = reinterpret_cast<const float2*>(x + (size_t)u * D_IN)[l];
    acc.x += t.x; acc.y += t.y;
  }
  int cnt[10] = {};
  for (int base = e0; base < e1; base += 64) {
    int e = base + l;
    int id = (e < e1) ? ids[csr[e]] : -1;
#pragma unroll
    for (int k = 0; k < 10; ++k)
      cnt[k] += __popcll(__ballot(id == k));
  }
  int myid = ids[v];
  unsigned short* row = agg1 + (size_t)v * K1P;
  unsigned* row32 = reinterpret_cast<unsigned*>(row);
  row32[l] = (unsigned)f2b(acc.x) | ((unsigned)f2b(acc.y) << 16);
  if (l < 32) {
    float val = 0.f;
#pragma unroll
    for (int kk = 0; kk < 10; ++kk)
      if (l == kk) val = (float)(cnt[kk] + (myid == kk ? 1 : 0));
    row[D_IN + l] = f2b(val);
  }
}

// ---------------- layer-2 aggregation (wave per node) ----------------
__global__ void k_agg2(const unsigned short* __restrict__ h,
                       const int* __restrict__ rowptr, const int* __restrict__ csr,
                       unsigned short* __restrict__ hs, int N) {
  int v = blockIdx.x * 4 + (threadIdx.x >> 6);
  if (v >= N) return;
  int l = threadIdx.x & 63;
  ushort4 t = reinterpret_cast<const ushort4*>(h + (size_t)v * HDIM)[l];
  float a0 = b2f(t.x), a1 = b2f(t.y), a2 = b2f(t.z), a3 = b2f(t.w);
  int e0 = rowptr[v], e1 = rowptr[v + 1];
  for (int e = e0; e < e1; ++e) {
    int u = csr[e];
    ushort4 s = reinterpret_cast<const ushort4*>(h + (size_t)u * HDIM)[l];
    a0 += b2f(s.x); a1 += b2f(s.y); a2 += b2f(s.z); a3 += b2f(s.w);
  }
  uint2 o;
  o.x = (unsigned)f2b(a0) | ((unsigned)f2b(a1) << 16);
  o.y = (unsigned)f2b(a2) | ((unsigned)f2b(a3) << 16);
  reinterpret_cast<uint2*>(hs + (size_t)v * HDIM)[l] = o;
}

// ---------------- weight prep (bf16, transposed, padded) ----------------
__global__ void k_wp1(const float* __restrict__ W1, unsigned short* __restrict__ Wpt) {
  int idx = blockIdx.x * 256 + threadIdx.x;          // 256*160
  int n = idx / K1P, k = idx % K1P;
  float v = (k < KRAW) ? W1[k * HDIM + n] : 0.f;
  Wpt[idx] = f2b(v);
}
__global__ void k_w2t(const float* __restrict__ W2, unsigned short* __restrict__ W2t) {
  int idx = blockIdx.x * 256 + threadIdx.x;          // 256*256
  int n = idx >> 8, k = idx & 255;
  W2t[idx] = f2b(W2[k * HDIM + n]);
}

// ---------------- GEMM1: h = relu(agg1 @ W1p + b1), bf16 MFMA ----------------
// BM=64, BN=128, K=160 fully staged. 4 waves in 2x2, wave tile 32x64.
__global__ __launch_bounds__(256, 2) void k_gemm1(
    const unsigned short* __restrict__ A, const unsigned short* __restrict__ Bt,
    const float* __restrict__ bias, unsigned short* __restrict__ H, int M) {
  constexpr int LDA = K1P + 8;  // 168 elems: 84-dword stride -> 2-way banks (free)
  __shared__ unsigned short a_s[64 * LDA];
  __shared__ unsigned short b_s[128 * LDA];
  int tid = threadIdx.x;
  int m0 = blockIdx.x * 64;
  int n0 = blockIdx.y * 128;
  for (int c = tid; c < 64 * 20; c += 256) {          // 20 x 16B chunks/row
    int row = c / 20, kc = c % 20;
    int grow = m0 + row;
    uint4 val = make_uint4(0, 0, 0, 0);
    if (grow < M) val = *reinterpret_cast<const uint4*>(A + (size_t)grow * K1P + kc * 8);
    *reinterpret_cast<uint4*>(&a_s[row * LDA + kc * 8]) = val;
  }
  for (int c = tid; c < 128 * 20; c += 256) {
    int row = c / 20, kc = c % 20;
    uint4 val = *reinterpret_cast<const uint4*>(Bt + (size_t)(n0 + row) * K1P + kc * 8);
    *reinterpret_cast<uint4*>(&b_s[row * LDA + kc * 8]) = val;
  }
  __syncthreads();
  int w = tid >> 6, l = tid & 63;
  int wm = w >> 1, wn = w & 1;
  int lrow = l & 15, lk = (l >> 4) * 8;
  f32x4 acc[2][4] = {};
#pragma unroll
  for (int ks = 0; ks < 5; ++ks) {
    int k0 = ks * 32;
    bf16x8 af[2], bfr[4];
#pragma unroll
    for (int mf = 0; mf < 2; ++mf)
      af[mf] = *reinterpret_cast<const bf16x8*>(&a_s[(wm * 32 + mf * 16 + lrow) * LDA + k0 + lk]);
#pragma unroll
    for (int nf = 0; nf < 4; ++nf)
      bfr[nf] = *reinterpret_cast<const bf16x8*>(&b_s[(wn * 64 + nf * 16 + lrow) * LDA + k0 + lk]);
#pragma unroll
    for (int mf = 0; mf < 2; ++mf)
#pragma unroll
      for (int nf = 0; nf < 4; ++nf)
        acc[mf][nf] = __builtin_amdgcn_mfma_f32_16x16x32_bf16(af[mf], bfr[nf], acc[mf][nf], 0, 0, 0);
  }
#pragma unroll
  for (int mf = 0; mf < 2; ++mf)
#pragma unroll
    for (int q = 0; q < 4; ++q) {
      int grow = m0 + wm * 32 + mf * 16 + (l >> 4) * 4 + q;   // verified C/D layout
      if (grow >= M) continue;
#pragma unroll
      for (int nf = 0; nf < 4; ++nf) {
        int col = n0 + wn * 64 + nf * 16 + lrow;
        float vv = acc[mf][nf][q] + bias[col];
        H[(size_t)grow * HDIM + col] = f2b(vv > 0.f ? vv : 0.f);
      }
    }
}

// ---------------- GEMM2 + fused segment pooling ----------------
// out[g] += relu(hsum @ W2 + b2) summed over rows of graph g.
// BM=64, BN=64, K=256 fully staged. LDS segment-reduce, ~nseg*64 global atomics/block.
__global__ __launch_bounds__(256, 2) void k_gemm2(
    const unsigned short* __restrict__ A, const unsigned short* __restrict__ Bt,
    const float* __restrict__ bias, const int* __restrict__ bids,
    float* __restrict__ out, int M) {
  constexpr int LDA = HDIM + 8;  // 264 elems
  __shared__ unsigned short a_s[64 * LDA];
  __shared__ unsigned short b_s[64 * LDA];
  __shared__ int bt_[64];
  __shared__ int segidx[64];
  __shared__ int segrow[64];
  __shared__ int nseg_s;
  int tid = threadIdx.x;
  int m0 = blockIdx.x * 64;
  int n0 = blockIdx.y * 64;
  if (tid < 64) {
    int grow = m0 + tid;
    bt_[tid] = bids[grow < M ? grow : (M - 1)];
  }
  for (int c = tid; c < 64 * 32; c += 256) {
    int row = c >> 5, kc = c & 31;
    int grow = m0 + row;
    uint4 val = make_uint4(0, 0, 0, 0);
    if (grow < M) val = *reinterpret_cast<const uint4*>(A + (size_t)grow * HDIM + kc * 8);
    *reinterpret_cast<uint4*>(&a_s[row * LDA + kc * 8]) = val;
  }
  for (int c = tid; c < 64 * 32; c += 256) {
    int row = c >> 5, kc = c & 31;
    uint4 val = *reinterpret_cast<const uint4*>(Bt + (size_t)(n0 + row) * HDIM + kc * 8);
    *reinterpret_cast<uint4*>(&b_s[row * LDA + kc * 8]) = val;
  }
  __syncthreads();
  int w = tid >> 6, l = tid & 63;
  int wm = w >> 1, wn = w & 1;
  int lrow = l & 15, lk = (l >> 4) * 8;
  f32x4 acc[2][2] = {};
#pragma unroll
  for (int ks = 0; ks < 8; ++ks) {
    int k0 = ks * 32;
    bf16x8 af[2], bfr[2];
#pragma unroll
    for (int mf = 0; mf < 2; ++mf)
      af[mf] = *reinterpret_cast<const bf16x8*>(&a_s[(wm * 32 + mf * 16 + lrow) * LDA + k0 + lk]);
#pragma unroll
    for (int nf = 0; nf < 2; ++nf)
      bfr[nf] = *reinterpret_cast<const bf16x8*>(&b_s[(wn * 32 + nf * 16 + lrow) * LDA + k0 + lk]);
#pragma unroll
    for (int mf = 0; mf < 2; ++mf)
#pragma unroll
      for (int nf = 0; nf < 2; ++nf)
        acc[mf][nf] = __builtin_amdgcn_mfma_f32_16x16x32_bf16(af[mf], bfr[nf], acc[mf][nf], 0, 0, 0);
  }
  // ---- pooling epilogue ----
  __syncthreads();                                   // all waves done reading a_s
  float* pool = reinterpret_cast<float*>(a_s);       // 64 segs x stride 65 = 16.6KB
  for (int i = tid; i < 64 * 65; i += 256) pool[i] = 0.f;
  if (tid < 64) {
    int s = 0;
    for (int i = 1; i <= tid; ++i) s += (bt_[i] != bt_[i - 1]) ? 1 : 0;
    segidx[tid] = s;
    if (tid == 0 || bt_[tid] != bt_[tid - 1]) segrow[s] = tid;
    if (tid == 63) nseg_s = s + 1;
  }
  __syncthreads();
  float bv[2];
  bv[0] = bias[n0 + wn * 32 + lrow];
  bv[1] = bias[n0 + wn * 32 + 16 + lrow];
#pragma unroll
  for (int mf = 0; mf < 2; ++mf)
#pragma unroll
    for (int q = 0; q < 4; ++q) {
      int rl = wm * 32 + mf * 16 + (l >> 4) * 4 + q;
      if (m0 + rl >= M) continue;
      int s = segidx[rl];
#pragma unroll
      for (int nf = 0; nf < 2; ++nf) {
        float vv = acc[mf][nf][q] + bv[nf];
        if (vv > 0.f)
          atomicAdd(&pool[s * 65 + wn * 32 + nf * 16 + lrow], vv);
      }
    }
  __syncthreads();
  if (tid < 64) {
    int nseg = nseg_s;
    for (int s = 0; s < nseg; ++s) {
      float vv = pool[s * 65 + tid];
      if (vv != 0.f) {
        int g = bt_[segrow[s]];
        atomicAdd(&out[(size_t)g * HDIM + n0 + tid], vv);
      }
    }
  }
}

extern "C" void kernel_launch(void* const* d_in, const int* in_sizes, int n_in,
                              void* d_out, int out_size, void* d_ws, size_t ws_size,
                              hipStream_t stream) {
  const float* x    = (const float*)d_in[0];
  const int*   ei   = (const int*)d_in[1];
  const int*   bids = (const int*)d_in[2];
  const float* W1   = (const float*)d_in[3];
  const float* b1   = (const float*)d_in[4];
  const float* W2   = (const float*)d_in[5];
  const float* b2   = (const float*)d_in[6];
  float* out = (float*)d_out;

  const int N = in_sizes[2];
  const int E = in_sizes[1] / 2;
  const int* src = ei;
  const int* dst = ei + E;

  char* ws = (char*)d_ws;
  size_t off = 0;
  auto alloc = [&](size_t bytes) {
    size_t o = off;
    off = (off + bytes + 255) & ~(size_t)255;
    return o;
  };
  float* r      = (float*)(ws + alloc((size_t)N * 4));
  int*   ids    = (int*)(ws + alloc((size_t)N * 4));
  int*   start  = (int*)(ws + alloc((size_t)NGRAPH * 4));
  int*   cnt    = (int*)(ws + alloc((size_t)NGRAPH * 4));
  int*   deg    = (int*)(ws + alloc((size_t)N * 4));
  int*   rowptr = (int*)(ws + alloc((size_t)(N + 1) * 4));
  int*   fill   = (int*)(ws + alloc((size_t)N * 4));
  int*   bsum   = (int*)(ws + alloc(512 * 4));
  int*   csr    = (int*)(ws + alloc((size_t)E * 4));
  unsigned short* Wpt  = (unsigned short*)(ws + alloc((size_t)HDIM * K1P * 2));
  unsigned short* W2t  = (unsigned short*)(ws + alloc((size_t)HDIM * HDIM * 2));
  unsigned short* agg1 = (unsigned short*)(ws + alloc((size_t)N * K1P * 2));
  unsigned short* h    = (unsigned short*)(ws + alloc((size_t)N * HDIM * 2));
  unsigned short* hsum = (unsigned short*)(ws + alloc((size_t)N * HDIM * 2));
  (void)ws_size;

  hipMemsetAsync(cnt, 0, (size_t)NGRAPH * 4, stream);
  hipMemsetAsync(deg, 0, (size_t)N * 4, stream);
  hipMemsetAsync(fill, 0, (size_t)N * 4, stream);
  hipMemsetAsync(out, 0, (size_t)out_size * 4, stream);

  const int nb = (N + 255) / 256;  // 391
  k_prep<<<nb, 256, 0, stream>>>(bids, r, start, cnt, N);
  k_wp1<<<(HDIM * K1P) / 256, 256, 0, stream>>>(W1, Wpt);
  k_w2t<<<(HDIM * HDIM) / 256, 256, 0, stream>>>(W2, W2t);
  k_deg<<<(E + 255) / 256, 256, 0, stream>>>(dst, deg, E);
  k_scan1<<<nb, 256, 0, stream>>>(deg, rowptr, bsum, N);
  k_scan2<<<1, 512, 0, stream>>>(bsum, nb);
  k_scan3<<<nb, 256, 0, stream>>>(rowptr, bsum, N, E);
  k_scatter<<<(E + 255) / 256, 256, 0, stream>>>(src, dst, rowptr, fill, csr, E);
  k_rank<<<NGRAPH, 64, 0, stream>>>(r, start, cnt, ids);
  k_agg1<<<(N + 3) / 4, 256, 0, stream>>>(x, ids, rowptr, csr, agg1, N);

  dim3 g1((N + 63) / 64, 2);
  k_gemm1<<<g1, 256, 0, stream>>>(agg1, Wpt, b1, h, N);

  k_agg2<<<(N + 3) / 4, 256, 0, stream>>>(h, rowptr, csr, hsum, N);

  dim3 g2((N + 63) / 64, 4);
  k_gemm2<<<g2, 256, 0, stream>>>(hsum, W2t, b2, bids, out, N);
}

// Round 3
// 483.659 us; speedup vs baseline: 3.3666x; 1.1859x over previous
//
#include <hip/hip_runtime.h>
#include <hip/hip_bf16.h>
#include <stdint.h>

// RPGNN: threefry ranks -> CSR -> bf16 gather-agg -> pipelined bf16 MFMA GEMMs
// GEMM structure: BM=64, BN=256 (A read once), BK=32 double-buffered via
// global_load_lds(16B), 4 waves, fused segment pooling in GEMM2.

#define D_IN   128
#define KRAW   138
#define K1P    160
#define HDIM   256
#define NGRAPH 2000
#define MAXSEG 8

typedef __bf16 bf16x8 __attribute__((ext_vector_type(8)));
typedef float  f32x4  __attribute__((ext_vector_type(4)));

__device__ __forceinline__ unsigned short f2b(float f) {
  __hip_bfloat16 h = __float2bfloat16(f);
  return __builtin_bit_cast(unsigned short, h);
}
__device__ __forceinline__ float b2f(unsigned u) {
  return __uint_as_float(u << 16);
}

__device__ __forceinline__ void glds16(const unsigned short* g, unsigned short* l) {
  __builtin_amdgcn_global_load_lds(
      (const __attribute__((address_space(1))) unsigned int*)g,
      (__attribute__((address_space(3))) unsigned int*)l, 16, 0, 0);
}

// ---------------- threefry2x32 (bit-exact JAX replica) ----------------
__device__ __forceinline__ unsigned rotl32(unsigned x, int r) {
  return (x << r) | (x >> (32 - r));
}
__device__ __forceinline__ void threefry2x32(unsigned k0, unsigned k1,
                                             unsigned x0, unsigned x1,
                                             unsigned& o0, unsigned& o1) {
  unsigned ks2 = k0 ^ k1 ^ 0x1BD11BDAu;
  unsigned ks[3] = {k0, k1, ks2};
  x0 += ks[0]; x1 += ks[1];
  const int rotA[4] = {13, 15, 26, 6};
  const int rotB[4] = {17, 29, 16, 24};
#pragma unroll
  for (int i = 0; i < 5; ++i) {
    const int* rot = (i & 1) ? rotB : rotA;
#pragma unroll
    for (int j = 0; j < 4; ++j) {
      x0 += x1; x1 = rotl32(x1, rot[j]); x1 ^= x0;
    }
    x0 += ks[(i + 1) % 3];
    x1 += ks[(i + 2) % 3] + (unsigned)(i + 1);
  }
  o0 = x0; o1 = x1;
}

// prep (per-node PRNG + segment starts/counts) merged with degree histogram
__global__ void k_prep2(const int* __restrict__ bids, const int* __restrict__ dst,
                        float* __restrict__ r, int* __restrict__ start,
                        int* __restrict__ cnt, int* __restrict__ deg, int N, int E) {
  int i = blockIdx.x * blockDim.x + threadIdx.x;
  if (i < E) atomicAdd(&deg[dst[i]], 1);
  if (i >= N) return;
  int half = N >> 1;
  if (i < half) {
    unsigned fk0, fk1;
    threefry2x32(0u, 42u, 0u, 0u, fk0, fk1);          // fold_in(key(42), 0)
    unsigned b0, b1v;
    threefry2x32(fk0, fk1, (unsigned)i, (unsigned)(i + half), b0, b1v);
    r[i]        = __uint_as_float((b0  >> 9) | 0x3f800000u) - 1.0f;
    r[i + half] = __uint_as_float((b1v >> 9) | 0x3f800000u) - 1.0f;
  }
  int g = bids[i];
  if (i == 0 || bids[i - 1] != g) start[g] = i;
  atomicAdd(&cnt[g], 1);
}

// rank within graph under key = float(g)+r, stable tie-break on index
__global__ void k_rank(const float* __restrict__ r, const int* __restrict__ start,
                       const int* __restrict__ cnt, int* __restrict__ ids) {
  int g = blockIdx.x;
  int st = start[g], n = cnt[g];
  if (n <= 0) return;
  float gf = (float)g;
  for (int t = threadIdx.x; t < n; t += blockDim.x) {
    int v = st + t;
    float kv = gf + r[v];
    int c = 0;
    for (int u0 = 0; u0 < n; ++u0) {
      int u = st + u0;
      float ku = gf + r[u];
      c += (int)((ku < kv) | ((ku == kv) & (u < v)));
    }
    ids[v] = c % 10;
  }
}

// ---------------- CSR build ----------------
__global__ void k_scan1(const int* __restrict__ deg, int* __restrict__ rowptr,
                        int* __restrict__ bsum, int N) {
  __shared__ int buf[256];
  int tid = threadIdx.x;
  int i = blockIdx.x * 256 + tid;
  int v = (i < N) ? deg[i] : 0;
  buf[tid] = v;
  __syncthreads();
  for (int off = 1; off < 256; off <<= 1) {
    int t = (tid >= off) ? buf[tid - off] : 0;
    __syncthreads();
    buf[tid] += t;
    __syncthreads();
  }
  if (i < N) rowptr[i] = buf[tid] - v;
  if (tid == 255) bsum[blockIdx.x] = buf[255];
}

__global__ void k_scan2(int* __restrict__ bsum, int nb) {
  __shared__ int buf[512];
  int tid = threadIdx.x;
  int v = (tid < nb) ? bsum[tid] : 0;
  buf[tid] = v;
  __syncthreads();
  for (int off = 1; off < 512; off <<= 1) {
    int t = (tid >= off) ? buf[tid - off] : 0;
    __syncthreads();
    buf[tid] += t;
    __syncthreads();
  }
  if (tid < nb) bsum[tid] = buf[tid] - v;
}

__global__ void k_scan3(int* __restrict__ rowptr, const int* __restrict__ bsum,
                        int N, int E) {
  int i = blockIdx.x * 256 + threadIdx.x;
  if (i < N) rowptr[i] += bsum[blockIdx.x];
  if (i == 0) rowptr[N] = E;
}

__global__ void k_scatter(const int* __restrict__ src, const int* __restrict__ dst,
                          const int* __restrict__ rowptr, int* __restrict__ fill,
                          int* __restrict__ csr, int E) {
  int e = blockIdx.x * 256 + threadIdx.x;
  if (e >= E) return;
  int d = dst[e];
  int pos = rowptr[d] + atomicAdd(&fill[d], 1);
  csr[pos] = src[e];
}

// ---------------- weight prep (bf16, transposed, padded) ----------------
__global__ void k_wprep(const float* __restrict__ W1, const float* __restrict__ W2,
                        unsigned short* __restrict__ Wpt, unsigned short* __restrict__ W2t) {
  int idx = blockIdx.x * 256 + threadIdx.x;
  if (idx < HDIM * K1P) {
    int n = idx / K1P, k = idx % K1P;
    Wpt[idx] = f2b(k < KRAW ? W1[k * HDIM + n] : 0.f);
  } else {
    int j = idx - HDIM * K1P;
    if (j < HDIM * HDIM) {
      int n = j >> 8, k = j & 255;
      W2t[j] = f2b(W2[k * HDIM + n]);
    }
  }
}

// ---------------- x -> bf16 (halves layer-1 gather bytes) ----------------
__global__ void k_xb(const float* __restrict__ x, unsigned short* __restrict__ xb, int n8) {
  int i = blockIdx.x * 256 + threadIdx.x;
  if (i >= n8) return;
  const float4* xp = reinterpret_cast<const float4*>(x) + (size_t)i * 2;
  float4 v0 = xp[0], v1 = xp[1];
  uint4 o;
  o.x = (unsigned)f2b(v0.x) | ((unsigned)f2b(v0.y) << 16);
  o.y = (unsigned)f2b(v0.z) | ((unsigned)f2b(v0.w) << 16);
  o.z = (unsigned)f2b(v1.x) | ((unsigned)f2b(v1.y) << 16);
  o.w = (unsigned)f2b(v1.z) | ((unsigned)f2b(v1.w) << 16);
  reinterpret_cast<uint4*>(xb)[i] = o;
}

// ---------------- layer-1 aggregation (wave per node, bf16 gather) ----------------
__global__ void k_agg1(const unsigned short* __restrict__ xb, const int* __restrict__ ids,
                       const int* __restrict__ rowptr, const int* __restrict__ csr,
                       unsigned short* __restrict__ agg1, int N) {
  int v = blockIdx.x * 4 + (threadIdx.x >> 6);
  if (v >= N) return;
  int l = threadIdx.x & 63;
  unsigned sv = reinterpret_cast<const unsigned*>(xb + (size_t)v * D_IN)[l];
  float a0 = b2f(sv & 0xffffu), a1 = b2f(sv >> 16);
  int e0 = rowptr[v], e1 = rowptr[v + 1];
  for (int e = e0; e < e1; ++e) {
    int u = csr[e];
    unsigned t = reinterpret_cast<const unsigned*>(xb + (size_t)u * D_IN)[l];
    a0 += b2f(t & 0xffffu); a1 += b2f(t >> 16);
  }
  int cnt10[10] = {};
  for (int base = e0; base < e1; base += 64) {
    int e = base + l;
    int id = (e < e1) ? ids[csr[e]] : -1;
#pragma unroll
    for (int k = 0; k < 10; ++k)
      cnt10[k] += (int)__popcll(__ballot(id == k));
  }
  int myid = ids[v];
  unsigned* row32 = reinterpret_cast<unsigned*>(agg1 + (size_t)v * K1P);
  row32[l] = (unsigned)f2b(a0) | ((unsigned)f2b(a1) << 16);
  if (l < 16) {
    float v0 = 0.f, v1 = 0.f;
#pragma unroll
    for (int kk = 0; kk < 10; ++kk) {
      float cv = (float)(cnt10[kk] + (myid == kk ? 1 : 0));
      if (2 * l == kk) v0 = cv;
      if (2 * l + 1 == kk) v1 = cv;
    }
    row32[64 + l] = (unsigned)f2b(v0) | ((unsigned)f2b(v1) << 16);
  }
}

// ---------------- layer-2 aggregation (wave per node) ----------------
__global__ void k_agg2(const unsigned short* __restrict__ h,
                       const int* __restrict__ rowptr, const int* __restrict__ csr,
                       unsigned short* __restrict__ hs, int N) {
  int v = blockIdx.x * 4 + (threadIdx.x >> 6);
  if (v >= N) return;
  int l = threadIdx.x & 63;
  ushort4 t = reinterpret_cast<const ushort4*>(h + (size_t)v * HDIM)[l];
  float a0 = b2f(t.x), a1 = b2f(t.y), a2 = b2f(t.z), a3 = b2f(t.w);
  int e0 = rowptr[v], e1 = rowptr[v + 1];
  for (int e = e0; e < e1; ++e) {
    int u = csr[e];
    ushort4 s = reinterpret_cast<const ushort4*>(h + (size_t)u * HDIM)[l];
    a0 += b2f(s.x); a1 += b2f(s.y); a2 += b2f(s.z); a3 += b2f(s.w);
  }
  uint2 o;
  o.x = (unsigned)f2b(a0) | ((unsigned)f2b(a1) << 16);
  o.y = (unsigned)f2b(a2) | ((unsigned)f2b(a3) << 16);
  reinterpret_cast<uint2*>(hs + (size_t)v * HDIM)[l] = o;
}

// ---------------- pipelined bf16 MFMA GEMM ----------------
// BM=64, BN=256 (grid.y=1 -> A read once), BK=32 double-buffered via
// global_load_lds. 4 waves; wave w owns cols [w*64, w*64+64), all 64 rows.
// POOL: fused per-graph segment pooling (bids sorted).
template <int KTOT, bool POOL>
__global__ __launch_bounds__(256) void k_gemm(
    const unsigned short* __restrict__ A, const unsigned short* __restrict__ Bt,
    const float* __restrict__ bias, unsigned short* __restrict__ H,
    const int* __restrict__ bids, float* __restrict__ out, int M) {
  constexpr int NT = KTOT / 32;
  __shared__ __align__(16) unsigned short a_s[2][64 * 32];    // 8 KB
  __shared__ __align__(16) unsigned short b_s[2][256 * 32];   // 32 KB
  __shared__ int bt_[64];
  __shared__ int segidx_s[64];
  __shared__ int gseg[MAXSEG];
  __shared__ int nseg_sh;

  int tid = threadIdx.x;
  int w = tid >> 6, l = tid & 63;
  int m0 = blockIdx.x * 64;
  int lr = l & 15;

  f32x4 acc[4][4] = {};

  auto stage = [&](int buf, int k0) {
    {
      int row = m0 + w * 16 + (l >> 2);
      glds16(A + (size_t)row * KTOT + k0 + (l & 3) * 8, &a_s[buf][(w * 16) * 32]);
    }
#pragma unroll
    for (int j = 0; j < 4; ++j) {
      int n = w * 64 + j * 16 + (l >> 2);
      glds16(Bt + (size_t)n * KTOT + k0 + (l & 3) * 8, &b_s[buf][(w * 64 + j * 16) * 32]);
    }
  };

  stage(0, 0);
  __syncthreads();
  for (int t = 0; t < NT; ++t) {
    if (t + 1 < NT) stage((t + 1) & 1, (t + 1) * 32);
    const unsigned short* as = &a_s[t & 1][0];
    const unsigned short* bs = &b_s[t & 1][0];
    int lk = (l >> 4) * 8;
    bf16x8 af[4], bfr[4];
#pragma unroll
    for (int mf = 0; mf < 4; ++mf)
      af[mf] = *reinterpret_cast<const bf16x8*>(&as[(mf * 16 + lr) * 32 + lk]);
#pragma unroll
    for (int nf = 0; nf < 4; ++nf)
      bfr[nf] = *reinterpret_cast<const bf16x8*>(&bs[(w * 64 + nf * 16 + lr) * 32 + lk]);
#pragma unroll
    for (int mf = 0; mf < 4; ++mf)
#pragma unroll
      for (int nf = 0; nf < 4; ++nf)
        acc[mf][nf] = __builtin_amdgcn_mfma_f32_16x16x32_bf16(af[mf], bfr[nf], acc[mf][nf], 0, 0, 0);
    __syncthreads();
  }

  float bv[4];
#pragma unroll
  for (int nf = 0; nf < 4; ++nf) bv[nf] = bias[w * 64 + nf * 16 + lr];

  if (!POOL) {
#pragma unroll
    for (int mf = 0; mf < 4; ++mf)
#pragma unroll
      for (int q = 0; q < 4; ++q) {
        int grow = m0 + mf * 16 + (l >> 4) * 4 + q;   // verified C/D layout
        if (grow >= M) continue;
        size_t rowoff = (size_t)grow * HDIM + w * 64 + lr;
#pragma unroll
        for (int nf = 0; nf < 4; ++nf) {
          float vv = acc[mf][nf][q] + bv[nf];
          H[rowoff + nf * 16] = f2b(vv > 0.f ? vv : 0.f);
        }
      }
  } else {
    float* pool = reinterpret_cast<float*>(&a_s[0][0]);   // 4 waves x MAXSEG x 64 f32 = 8 KB
    if (tid < 64) bt_[tid] = bids[(m0 + tid) < M ? (m0 + tid) : (M - 1)];
    for (int i = tid; i < 4 * MAXSEG * 64; i += 256) pool[i] = 0.f;
    __syncthreads();
    if (tid < 64) {
      bool bnd = (tid > 0) && (bt_[tid] != bt_[tid - 1]);
      unsigned long long mask = __ballot(bnd);
      int s = (int)__popcll(mask & (~0ULL >> (63 - tid)));
      segidx_s[tid] = s;
      if ((tid == 0 || bnd) && s < MAXSEG) gseg[s] = bt_[tid];
      if (tid == 63) nseg_sh = s + 1;
    }
    __syncthreads();
    int nseg = nseg_sh;
    if (nseg <= MAXSEG) {
#pragma unroll
      for (int mf = 0; mf < 4; ++mf)
#pragma unroll
        for (int q = 0; q < 4; ++q) {
          int rl = mf * 16 + (l >> 4) * 4 + q;
          if (m0 + rl >= M) continue;
          float* pw = pool + (w * MAXSEG + segidx_s[rl]) * 64;
#pragma unroll
          for (int nf = 0; nf < 4; ++nf) {
            float vv = acc[mf][nf][q] + bv[nf];
            if (vv > 0.f) atomicAdd(&pw[nf * 16 + lr], vv);
          }
        }
      __syncthreads();
      int c = tid & 63, ww = tid >> 6;
      for (int s = 0; s < nseg; ++s) {
        float vv = pool[(ww * MAXSEG + s) * 64 + c];
        if (vv != 0.f) atomicAdd(&out[(size_t)gseg[s] * HDIM + ww * 64 + c], vv);
      }
    } else {  // pathological fallback (block-uniform branch)
#pragma unroll
      for (int mf = 0; mf < 4; ++mf)
#pragma unroll
        for (int q = 0; q < 4; ++q) {
          int rl = mf * 16 + (l >> 4) * 4 + q;
          if (m0 + rl >= M) continue;
          int g = bt_[rl];
#pragma unroll
          for (int nf = 0; nf < 4; ++nf) {
            float vv = acc[mf][nf][q] + bv[nf];
            if (vv > 0.f) atomicAdd(&out[(size_t)g * HDIM + w * 64 + nf * 16 + lr], vv);
          }
        }
    }
  }
}

extern "C" void kernel_launch(void* const* d_in, const int* in_sizes, int n_in,
                              void* d_out, int out_size, void* d_ws, size_t ws_size,
                              hipStream_t stream) {
  const float* x    = (const float*)d_in[0];
  const int*   ei   = (const int*)d_in[1];
  const int*   bids = (const int*)d_in[2];
  const float* W1   = (const float*)d_in[3];
  const float* b1   = (const float*)d_in[4];
  const float* W2   = (const float*)d_in[5];
  const float* b2   = (const float*)d_in[6];
  float* out = (float*)d_out;

  const int N = in_sizes[2];
  const int E = in_sizes[1] / 2;
  const int* src = ei;
  const int* dst = ei + E;

  char* ws = (char*)d_ws;
  size_t off = 0;
  auto alloc = [&](size_t bytes) {
    size_t o = off;
    off = (off + bytes + 255) & ~(size_t)255;
    return o;
  };
  float* r      = (float*)(ws + alloc((size_t)N * 4));
  int*   ids    = (int*)(ws + alloc((size_t)N * 4));
  int*   start  = (int*)(ws + alloc((size_t)NGRAPH * 4));
  int*   cnt    = (int*)(ws + alloc((size_t)NGRAPH * 4));
  int*   deg    = (int*)(ws + alloc((size_t)N * 4));
  int*   rowptr = (int*)(ws + alloc((size_t)(N + 1) * 4));
  int*   fill   = (int*)(ws + alloc((size_t)N * 4));
  int*   bsum   = (int*)(ws + alloc(512 * 4));
  int*   csr    = (int*)(ws + alloc((size_t)E * 4));
  unsigned short* Wpt  = (unsigned short*)(ws + alloc((size_t)HDIM * K1P * 2));
  unsigned short* W2t  = (unsigned short*)(ws + alloc((size_t)HDIM * HDIM * 2));
  unsigned short* xb   = (unsigned short*)(ws + alloc((size_t)N * D_IN * 2));
  // +64 rows padding: GEMM staging reads past M up to the 64-row tile
  unsigned short* agg1 = (unsigned short*)(ws + alloc((size_t)(N + 64) * K1P * 2));
  unsigned short* h    = (unsigned short*)(ws + alloc((size_t)(N + 64) * HDIM * 2));
  unsigned short* hsum = (unsigned short*)(ws + alloc((size_t)(N + 64) * HDIM * 2));
  (void)ws_size;

  hipMemsetAsync(cnt, 0, (size_t)NGRAPH * 4, stream);
  hipMemsetAsync(deg, 0, (size_t)N * 4, stream);
  hipMemsetAsync(fill, 0, (size_t)N * 4, stream);
  hipMemsetAsync(out, 0, (size_t)out_size * 4, stream);

  const int nb = (N + 255) / 256;
  k_prep2<<<(E + 255) / 256, 256, 0, stream>>>(bids, dst, r, start, cnt, deg, N, E);
  k_wprep<<<(HDIM * K1P + HDIM * HDIM + 255) / 256, 256, 0, stream>>>(W1, W2, Wpt, W2t);
  k_xb<<<(N * 16 + 255) / 256, 256, 0, stream>>>(x, xb, N * 16);
  k_scan1<<<nb, 256, 0, stream>>>(deg, rowptr, bsum, N);
  k_scan2<<<1, 512, 0, stream>>>(bsum, nb);
  k_scan3<<<nb, 256, 0, stream>>>(rowptr, bsum, N, E);
  k_scatter<<<(E + 255) / 256, 256, 0, stream>>>(src, dst, rowptr, fill, csr, E);
  k_rank<<<NGRAPH, 64, 0, stream>>>(r, start, cnt, ids);
  k_agg1<<<(N + 3) / 4, 256, 0, stream>>>(xb, ids, rowptr, csr, agg1, N);

  k_gemm<K1P, false><<<(N + 63) / 64, 256, 0, stream>>>(agg1, Wpt, b1, h, nullptr, nullptr, N);

  k_agg2<<<(N + 3) / 4, 256, 0, stream>>>(h, rowptr, csr, hsum, N);

  k_gemm<HDIM, true><<<(N + 63) / 64, 256, 0, stream>>>(hsum, W2t, b2, nullptr, bids, out, N);
}

// Round 6
// 371.606 us; speedup vs baseline: 4.3817x; 1.3015x over previous
//
#include <hip/hip_runtime.h>
#include <hip/hip_bf16.h>
#include <stdint.h>

// RPGNN: threefry ranks -> CSR -> bf16 gather-agg -> persistent-B pipelined
// bf16 MFMA GEMMs (B resident in LDS once/block, A streamed 3-buffered with
// counted vmcnt; XOR-swizzled LDS; register segment-pooling in GEMM2).

#define D_IN   128
#define KRAW   138
#define K1     160   // A row stride, layer 1
#define B1ROW  192   // B padded row (elems) layer 1: 384B rows -> XOR swizzle valid
#define HDIM   256
#define NGRAPH 2000

typedef __bf16 bf16x8 __attribute__((ext_vector_type(8)));
typedef float  f32x4  __attribute__((ext_vector_type(4)));

__device__ __forceinline__ unsigned short f2b(float f) {
  __hip_bfloat16 h = __float2bfloat16(f);
  return __builtin_bit_cast(unsigned short, h);
}
__device__ __forceinline__ float blo(unsigned p) { return __uint_as_float(p << 16); }
__device__ __forceinline__ float bhi(unsigned p) { return __uint_as_float(p & 0xffff0000u); }

__device__ __forceinline__ void glds16(const unsigned short* g, unsigned short* l) {
  __builtin_amdgcn_global_load_lds(
      (const __attribute__((address_space(1))) unsigned int*)g,
      (__attribute__((address_space(3))) unsigned int*)l, 16, 0, 0);
}

// ---------------- threefry2x32 (bit-exact JAX replica) ----------------
__device__ __forceinline__ unsigned rotl32(unsigned x, int r) {
  return (x << r) | (x >> (32 - r));
}
__device__ __forceinline__ void threefry2x32(unsigned k0, unsigned k1,
                                             unsigned x0, unsigned x1,
                                             unsigned& o0, unsigned& o1) {
  unsigned ks2 = k0 ^ k1 ^ 0x1BD11BDAu;
  unsigned ks[3] = {k0, k1, ks2};
  x0 += ks[0]; x1 += ks[1];
  const int rotA[4] = {13, 15, 26, 6};
  const int rotB[4] = {17, 29, 16, 24};
#pragma unroll
  for (int i = 0; i < 5; ++i) {
    const int* rot = (i & 1) ? rotB : rotA;
#pragma unroll
    for (int j = 0; j < 4; ++j) {
      x0 += x1; x1 = rotl32(x1, rot[j]); x1 ^= x0;
    }
    x0 += ks[(i + 1) % 3];
    x1 += ks[(i + 2) % 3] + (unsigned)(i + 1);
  }
  o0 = x0; o1 = x1;
}

__global__ void k_prep2(const int* __restrict__ bids, const int* __restrict__ dst,
                        float* __restrict__ r, int* __restrict__ start,
                        int* __restrict__ cnt, int* __restrict__ deg, int N, int E) {
  int i = blockIdx.x * blockDim.x + threadIdx.x;
  if (i < E) atomicAdd(&deg[dst[i]], 1);
  if (i >= N) return;
  int half = N >> 1;
  if (i < half) {
    unsigned fk0, fk1;
    threefry2x32(0u, 42u, 0u, 0u, fk0, fk1);          // fold_in(key(42), 0)
    unsigned b0, b1v;
    threefry2x32(fk0, fk1, (unsigned)i, (unsigned)(i + half), b0, b1v);
    r[i]        = __uint_as_float((b0  >> 9) | 0x3f800000u) - 1.0f;
    r[i + half] = __uint_as_float((b1v >> 9) | 0x3f800000u) - 1.0f;
  }
  int g = bids[i];
  if (i == 0 || bids[i - 1] != g) start[g] = i;
  atomicAdd(&cnt[g], 1);
}

// rank within graph under key = float(g)+r, stable tie-break on index
__global__ void k_rank(const float* __restrict__ r, const int* __restrict__ start,
                       const int* __restrict__ cnt, int* __restrict__ ids) {
  int g = blockIdx.x;
  int st = start[g], n = cnt[g];
  if (n <= 0) return;
  float gf = (float)g;
  for (int t = threadIdx.x; t < n; t += blockDim.x) {
    int v = st + t;
    float kv = gf + r[v];
    int c = 0;
    for (int u0 = 0; u0 < n; ++u0) {
      int u = st + u0;
      float ku = gf + r[u];
      c += (int)((ku < kv) | ((ku == kv) & (u < v)));
    }
    ids[v] = c % 10;
  }
}

// ---------------- CSR build ----------------
__global__ void k_scan1(const int* __restrict__ deg, int* __restrict__ rowptr,
                        int* __restrict__ bsum, int N) {
  __shared__ int buf[256];
  int tid = threadIdx.x;
  int i = blockIdx.x * 256 + tid;
  int v = (i < N) ? deg[i] : 0;
  buf[tid] = v;
  __syncthreads();
  for (int off = 1; off < 256; off <<= 1) {
    int t = (tid >= off) ? buf[tid - off] : 0;
    __syncthreads();
    buf[tid] += t;
    __syncthreads();
  }
  if (i < N) rowptr[i] = buf[tid] - v;
  if (tid == 255) bsum[blockIdx.x] = buf[255];
}

__global__ void k_scan2(int* __restrict__ bsum, int nb) {
  __shared__ int buf[512];
  int tid = threadIdx.x;
  int v = (tid < nb) ? bsum[tid] : 0;
  buf[tid] = v;
  __syncthreads();
  for (int off = 1; off < 512; off <<= 1) {
    int t = (tid >= off) ? buf[tid - off] : 0;
    __syncthreads();
    buf[tid] += t;
    __syncthreads();
  }
  if (tid < nb) bsum[tid] = buf[tid] - v;
}

__global__ void k_scan3(int* __restrict__ rowptr, const int* __restrict__ bsum,
                        int N, int E) {
  int i = blockIdx.x * 256 + threadIdx.x;
  if (i < N) rowptr[i] += bsum[blockIdx.x];
  if (i == 0) rowptr[N] = E;
}

__global__ void k_scatter(const int* __restrict__ src, const int* __restrict__ dst,
                          const int* __restrict__ rowptr, int* __restrict__ fill,
                          int* __restrict__ csr, int E) {
  int e = blockIdx.x * 256 + threadIdx.x;
  if (e >= E) return;
  int d = dst[e];
  int pos = rowptr[d] + atomicAdd(&fill[d], 1);
  csr[pos] = src[e];
}

// ---------------- x->bf16 + weight prep (merged) ----------------
__global__ void k_pre(const float* __restrict__ x, const float* __restrict__ W1,
                      const float* __restrict__ W2, unsigned short* __restrict__ xb,
                      unsigned short* __restrict__ Wpt, unsigned short* __restrict__ W2t,
                      int n8, int xbb) {
  int bid = blockIdx.x;
  int tid = threadIdx.x;
  if (bid < xbb) {
    int i = bid * 256 + tid;
    if (i >= n8) return;
    const float4* xp = reinterpret_cast<const float4*>(x) + (size_t)i * 2;
    float4 v0 = xp[0], v1 = xp[1];
    uint4 o;
    o.x = (unsigned)f2b(v0.x) | ((unsigned)f2b(v0.y) << 16);
    o.y = (unsigned)f2b(v0.z) | ((unsigned)f2b(v0.w) << 16);
    o.z = (unsigned)f2b(v1.x) | ((unsigned)f2b(v1.y) << 16);
    o.w = (unsigned)f2b(v1.z) | ((unsigned)f2b(v1.w) << 16);
    reinterpret_cast<uint4*>(xb)[i] = o;
  } else {
    int j = (bid - xbb) * 256 + tid;
    if (j < HDIM * B1ROW) {
      int n = j / B1ROW, k = j % B1ROW;
      Wpt[j] = f2b(k < KRAW ? W1[k * HDIM + n] : 0.f);
    } else {
      int j2 = j - HDIM * B1ROW;
      if (j2 < HDIM * HDIM) {
        int n = j2 >> 8, k = j2 & 255;
        W2t[j2] = f2b(W2[k * HDIM + n]);
      }
    }
  }
}

// ---------------- layer-1 aggregation (wave/node, 4x-unrolled gather) ----------------
__global__ void k_agg1(const unsigned short* __restrict__ xb, const int* __restrict__ ids,
                       const int* __restrict__ rowptr, const int* __restrict__ csr,
                       unsigned short* __restrict__ agg1, int N) {
  int v = blockIdx.x * 4 + (threadIdx.x >> 6);
  if (v >= N) return;
  int l = threadIdx.x & 63;
  const unsigned* xbase = reinterpret_cast<const unsigned*>(xb);
  unsigned sv = xbase[(size_t)v * 64 + l];
  float a0 = blo(sv), a1 = bhi(sv);
  int e0 = rowptr[v], e1 = rowptr[v + 1];
  int e = e0;
  for (; e + 4 <= e1; e += 4) {
    int u0 = csr[e], u1 = csr[e + 1], u2 = csr[e + 2], u3 = csr[e + 3];
    unsigned t0 = xbase[(size_t)u0 * 64 + l];
    unsigned t1 = xbase[(size_t)u1 * 64 + l];
    unsigned t2 = xbase[(size_t)u2 * 64 + l];
    unsigned t3 = xbase[(size_t)u3 * 64 + l];
    a0 += blo(t0) + blo(t1) + blo(t2) + blo(t3);
    a1 += bhi(t0) + bhi(t1) + bhi(t2) + bhi(t3);
  }
  for (; e < e1; ++e) {
    unsigned t = xbase[(size_t)csr[e] * 64 + l];
    a0 += blo(t); a1 += bhi(t);
  }
  int cnt10[10] = {};
  for (int base = e0; base < e1; base += 64) {
    int ee = base + l;
    int id = (ee < e1) ? ids[csr[ee]] : -1;
#pragma unroll
    for (int k = 0; k < 10; ++k)
      cnt10[k] += (int)__popcll(__ballot(id == k));
  }
  int myid = ids[v];
  unsigned* row32 = reinterpret_cast<unsigned*>(agg1 + (size_t)v * K1);
  row32[l] = (unsigned)f2b(a0) | ((unsigned)f2b(a1) << 16);
  if (l < 16) {
    float v0 = 0.f, v1 = 0.f;
#pragma unroll
    for (int kk = 0; kk < 10; ++kk) {
      float cv = (float)(cnt10[kk] + (myid == kk ? 1 : 0));
      if (2 * l == kk) v0 = cv;
      if (2 * l + 1 == kk) v1 = cv;
    }
    row32[64 + l] = (unsigned)f2b(v0) | ((unsigned)f2b(v1) << 16);
  }
}

// ---------------- layer-2 aggregation (wave/node, 4x-unrolled gather) ----------------
__global__ void k_agg2(const unsigned short* __restrict__ h,
                       const int* __restrict__ rowptr, const int* __restrict__ csr,
                       unsigned short* __restrict__ hs, int N) {
  int v = blockIdx.x * 4 + (threadIdx.x >> 6);
  if (v >= N) return;
  int l = threadIdx.x & 63;
  const uint2* base = reinterpret_cast<const uint2*>(h);
  uint2 t = base[(size_t)v * 64 + l];
  float a0 = blo(t.x), a1 = bhi(t.x), a2 = blo(t.y), a3 = bhi(t.y);
  int e0 = rowptr[v], e1 = rowptr[v + 1];
  int e = e0;
  for (; e + 4 <= e1; e += 4) {
    int u0 = csr[e], u1 = csr[e + 1], u2 = csr[e + 2], u3 = csr[e + 3];
    uint2 s0 = base[(size_t)u0 * 64 + l];
    uint2 s1 = base[(size_t)u1 * 64 + l];
    uint2 s2 = base[(size_t)u2 * 64 + l];
    uint2 s3 = base[(size_t)u3 * 64 + l];
    a0 += blo(s0.x) + blo(s1.x) + blo(s2.x) + blo(s3.x);
    a1 += bhi(s0.x) + bhi(s1.x) + bhi(s2.x) + bhi(s3.x);
    a2 += blo(s0.y) + blo(s1.y) + blo(s2.y) + blo(s3.y);
    a3 += bhi(s0.y) + bhi(s1.y) + bhi(s2.y) + bhi(s3.y);
  }
  for (; e < e1; ++e) {
    uint2 s = base[(size_t)csr[e] * 64 + l];
    a0 += blo(s.x); a1 += bhi(s.x); a2 += blo(s.y); a3 += bhi(s.y);
  }
  uint2 o;
  o.x = (unsigned)f2b(a0) | ((unsigned)f2b(a1) << 16);
  o.y = (unsigned)f2b(a2) | ((unsigned)f2b(a3) << 16);
  reinterpret_cast<uint2*>(hs)[(size_t)v * 64 + l] = o;
}

// ---------------- persistent-B pipelined bf16 MFMA GEMM ----------------
// grid=256 blocks x 512 thr. B (256 x BROW) staged once, XOR-swizzled.
// A streamed per 128-row tile, BK=32, 3 buffers, counted vmcnt(1) prefetch.
// Waves 2(m) x 4(n): wave tile 64x64. POOL: register segment pooling.
template <int KT, int BROW, int NT, bool POOL>
__global__ __launch_bounds__(512, 1) void k_gemm(
    const unsigned short* __restrict__ A, const unsigned short* __restrict__ Bt,
    const float* __restrict__ bias, unsigned short* __restrict__ H,
    const int* __restrict__ bids, float* __restrict__ out, int M) {
  constexpr int ROWB = BROW * 2;  // B row bytes (multiple of 128)
  __shared__ __align__(16) unsigned short b_s[HDIM * BROW];
  __shared__ __align__(16) unsigned short a_s[3 * 4096];
  __shared__ int seg_l[POOL ? 128 : 1];
  __shared__ int gseg_l[POOL ? 128 : 1];
  __shared__ int wtot[2];
  __shared__ int nseg_sh;

  const int tid = threadIdx.x;
  const int w = tid >> 6, l = tid & 63;
  const int wm = w >> 2, wn = w & 3;
  const int lr = l & 15, lq = l >> 4, lk = lq * 8;
  const int b = blockIdx.x;
  const int TT = (M + 127) >> 7;
  const int ntb = (TT > b) ? ((TT - b + 255) >> 8) : 0;
  const int total = ntb * NT;

  // stage B once (inverse-swizzled source, linear LDS dest)
  constexpr int BITERS = BROW / 16;
#pragma unroll
  for (int it = 0; it < BITERS; ++it) {
    int d = (it * 512 + tid) * 16;
    int n = d / ROWB;
    int inrow = d - n * ROWB;
    int u = inrow ^ ((n & 7) << 4);
    glds16(Bt + (size_t)n * BROW + (u >> 1), b_s + (size_t)(it * 512 + w * 64) * 8);
  }
  auto stageA = [&](int s) {
    int buf = s - (s / 3) * 3;
    int m0 = (b + (s / NT) * 256) << 7;
    int k0 = (s % NT) * 32;
    int d = tid * 16;
    int u = d ^ (((d >> 7) & 7) << 4);
    int r = ((u >> 7) << 1) | ((u >> 6) & 1);
    int k = (u >> 1) & 31;
    glds16(A + (size_t)(m0 + r) * KT + k0 + k, a_s + buf * 4096 + w * 512);
  };
  if (total > 0) stageA(0);
  if (total > 1) stageA(1);
  if (total > 1) { asm volatile("s_waitcnt vmcnt(1)" ::: "memory"); }
  else           { asm volatile("s_waitcnt vmcnt(0)" ::: "memory"); }
  __builtin_amdgcn_s_barrier();
  __builtin_amdgcn_sched_barrier(0);

  float bv[4];
#pragma unroll
  for (int nf = 0; nf < 4; ++nf) bv[nf] = bias[wn * 64 + nf * 16 + lr];

  // A fragment LDS byte offsets (constant across k-steps)
  int aoff[4];
#pragma unroll
  for (int mf = 0; mf < 4; ++mf) {
    int R = wm * 64 + mf * 16 + lr;
    aoff[mf] = (((R >> 1) * 128 + (R & 1) * 64 + lk * 2) ^ (((R >> 1) & 7) << 4));
  }

  int s = 0;
  for (int ti = 0; ti < ntb; ++ti) {
    const int m0t = (b + ti * 256) << 7;
    f32x4 acc[4][4] = {};
    for (int ks = 0; ks < NT; ++ks, ++s) {
      const bool pre = (s + 2 < total);
      if (pre) stageA(s + 2);
      const char* ab = reinterpret_cast<const char*>(a_s) + (s - (s / 3) * 3) * 8192;
      bf16x8 af[4], bfr[4];
#pragma unroll
      for (int mf = 0; mf < 4; ++mf)
        af[mf] = *reinterpret_cast<const bf16x8*>(ab + aoff[mf]);
#pragma unroll
      for (int nf = 0; nf < 4; ++nf) {
        int n = wn * 64 + nf * 16 + lr;
        int bb = n * ROWB + (((ks * 32 + lk) * 2) ^ ((n & 7) << 4));
        bfr[nf] = *reinterpret_cast<const bf16x8*>(reinterpret_cast<const char*>(b_s) + bb);
      }
      __builtin_amdgcn_s_setprio(1);
#pragma unroll
      for (int mf = 0; mf < 4; ++mf)
#pragma unroll
        for (int nf = 0; nf < 4; ++nf)
          acc[mf][nf] = __builtin_amdgcn_mfma_f32_16x16x32_bf16(af[mf], bfr[nf], acc[mf][nf], 0, 0, 0);
      __builtin_amdgcn_s_setprio(0);
      if (pre) { asm volatile("s_waitcnt vmcnt(1)" ::: "memory"); }
      else     { asm volatile("s_waitcnt vmcnt(0)" ::: "memory"); }
      __builtin_amdgcn_s_barrier();
      __builtin_amdgcn_sched_barrier(0);
    }

    if constexpr (!POOL) {
      // h = relu(acc + bias), bf16
#pragma unroll
      for (int mf = 0; mf < 4; ++mf)
#pragma unroll
        for (int q = 0; q < 4; ++q) {
          int grow = m0t + wm * 64 + mf * 16 + lq * 4 + q;
          if (grow < M) {
            size_t ro = (size_t)grow * HDIM + wn * 64 + lr;
#pragma unroll
            for (int nf = 0; nf < 4; ++nf) {
              float vv = acc[mf][nf][q] + bv[nf];
              H[ro + nf * 16] = f2b(vv > 0.f ? vv : 0.f);
            }
          }
        }
    } else {
      // ---- register segment pooling ----
      if (tid < 128) {
        int i0 = m0t + tid; i0 = i0 < M ? i0 : M - 1;
        int i1 = m0t + tid - 1; i1 = i1 < M ? i1 : M - 1; i1 = i1 > 0 ? i1 : 0;
        int g = bids[i0];
        bool bnd = (tid > 0) && (g != bids[i1]);
        unsigned long long mb = __ballot(bnd);
        int lane = tid & 63;
        int incl = (int)__popcll(mb & (~0ULL >> (63 - lane)));
        seg_l[tid] = incl;
        if (lane == 63) wtot[tid >> 6] = incl;
      }
      asm volatile("s_waitcnt lgkmcnt(0)" ::: "memory");
      __builtin_amdgcn_s_barrier();
      __builtin_amdgcn_sched_barrier(0);
      if (tid < 128) {
        int sfin = seg_l[tid] + ((tid >= 64) ? wtot[0] : 0);
        seg_l[tid] = sfin;
        int i0 = m0t + tid; i0 = i0 < M ? i0 : M - 1;
        int i1 = m0t + tid - 1; i1 = i1 < M ? i1 : M - 1; i1 = i1 > 0 ? i1 : 0;
        int g = bids[i0];
        if (tid == 0 || g != bids[i1]) gseg_l[sfin] = g;
        if (tid == 127) nseg_sh = sfin + 1;
      }
      asm volatile("s_waitcnt lgkmcnt(0)" ::: "memory");
      __builtin_amdgcn_s_barrier();
      __builtin_amdgcn_sched_barrier(0);
      // relu+bias in-place
#pragma unroll
      for (int mf = 0; mf < 4; ++mf)
#pragma unroll
        for (int nf = 0; nf < 4; ++nf)
#pragma unroll
          for (int q = 0; q < 4; ++q) {
            float vv = acc[mf][nf][q] + bv[nf];
            acc[mf][nf][q] = vv > 0.f ? vv : 0.f;
          }
      int msg[16];
      bool mok[16];
#pragma unroll
      for (int mf = 0; mf < 4; ++mf)
#pragma unroll
        for (int q = 0; q < 4; ++q) {
          int R = wm * 64 + mf * 16 + lq * 4 + q;
          msg[mf * 4 + q] = seg_l[R];
          mok[mf * 4 + q] = (m0t + R) < M;
        }
      int nseg = nseg_sh;
      for (int sg = 0; sg < nseg; ++sg) {
        float v0 = 0.f, v1 = 0.f, v2 = 0.f, v3 = 0.f;
#pragma unroll
        for (int mf = 0; mf < 4; ++mf)
#pragma unroll
          for (int q = 0; q < 4; ++q) {
            if ((msg[mf * 4 + q] == sg) & mok[mf * 4 + q]) {
              v0 += acc[mf][0][q]; v1 += acc[mf][1][q];
              v2 += acc[mf][2][q]; v3 += acc[mf][3][q];
            }
          }
        v0 += __shfl_xor(v0, 16); v0 += __shfl_xor(v0, 32);
        v1 += __shfl_xor(v1, 16); v1 += __shfl_xor(v1, 32);
        v2 += __shfl_xor(v2, 16); v2 += __shfl_xor(v2, 32);
        v3 += __shfl_xor(v3, 16); v3 += __shfl_xor(v3, 32);
        if (lq == 0) {
          float* op = out + (size_t)gseg_l[sg] * HDIM + wn * 64 + lr;
          atomicAdd(&op[0],  v0);
          atomicAdd(&op[16], v1);
          atomicAdd(&op[32], v2);
          atomicAdd(&op[48], v3);
        }
      }
      __builtin_amdgcn_s_barrier();   // protect seg_l/gseg_l before next tile
      __builtin_amdgcn_sched_barrier(0);
    }
  }
}

extern "C" void kernel_launch(void* const* d_in, const int* in_sizes, int n_in,
                              void* d_out, int out_size, void* d_ws, size_t ws_size,
                              hipStream_t stream) {
  const float* x    = (const float*)d_in[0];
  const int*   ei   = (const int*)d_in[1];
  const int*   bids = (const int*)d_in[2];
  const float* W1   = (const float*)d_in[3];
  const float* b1   = (const float*)d_in[4];
  const float* W2   = (const float*)d_in[5];
  const float* b2   = (const float*)d_in[6];
  float* out = (float*)d_out;

  const int N = in_sizes[2];
  const int E = in_sizes[1] / 2;
  const int* src = ei;
  const int* dst = ei + E;

  char* ws = (char*)d_ws;
  size_t off = 0;
  auto alloc = [&](size_t bytes) {
    size_t o = off;
    off = (off + bytes + 255) & ~(size_t)255;
    return o;
  };
  float* r      = (float*)(ws + alloc((size_t)N * 4));
  int*   ids    = (int*)(ws + alloc((size_t)N * 4));
  int*   start  = (int*)(ws + alloc((size_t)NGRAPH * 4));
  int*   cnt    = (int*)(ws + alloc((size_t)NGRAPH * 4));
  int*   deg    = (int*)(ws + alloc((size_t)N * 4));
  int*   fill   = (int*)(ws + alloc((size_t)N * 4));
  int*   rowptr = (int*)(ws + alloc((size_t)(N + 1) * 4));
  int*   bsum   = (int*)(ws + alloc(512 * 4));
  int*   csr    = (int*)(ws + alloc((size_t)E * 4));
  unsigned short* Wpt  = (unsigned short*)(ws + alloc((size_t)HDIM * B1ROW * 2));
  unsigned short* W2t  = (unsigned short*)(ws + alloc((size_t)HDIM * HDIM * 2));
  unsigned short* xb   = (unsigned short*)(ws + alloc((size_t)N * D_IN * 2));
  // +128 rows padding: GEMM staging reads up to the 128-row tile past M
  unsigned short* agg1 = (unsigned short*)(ws + alloc((size_t)(N + 128) * K1 * 2));
  unsigned short* h    = (unsigned short*)(ws + alloc((size_t)(N + 128) * HDIM * 2));
  unsigned short* hsum = (unsigned short*)(ws + alloc((size_t)(N + 128) * HDIM * 2));
  (void)ws_size;

  // cnt/deg/fill are contiguous in ws: single memset over the span
  size_t zspan = (size_t)((char*)(fill + N) - (char*)cnt);
  hipMemsetAsync(cnt, 0, zspan, stream);
  hipMemsetAsync(out, 0, (size_t)out_size * 4, stream);

  const int nb = (N + 255) / 256;
  const int n8 = N * 16;
  const int xbb = (n8 + 255) / 256;
  const int wb = (HDIM * B1ROW + HDIM * HDIM + 255) / 256;

  k_prep2<<<(E + 255) / 256, 256, 0, stream>>>(bids, dst, r, start, cnt, deg, N, E);
  k_pre<<<xbb + wb, 256, 0, stream>>>(x, W1, W2, xb, Wpt, W2t, n8, xbb);
  k_scan1<<<nb, 256, 0, stream>>>(deg, rowptr, bsum, N);
  k_scan2<<<1, 512, 0, stream>>>(bsum, nb);
  k_scan3<<<nb, 256, 0, stream>>>(rowptr, bsum, N, E);
  k_scatter<<<(E + 255) / 256, 256, 0, stream>>>(src, dst, rowptr, fill, csr, E);
  k_rank<<<NGRAPH, 64, 0, stream>>>(r, start, cnt, ids);
  k_agg1<<<(N + 3) / 4, 256, 0, stream>>>(xb, ids, rowptr, csr, agg1, N);

  k_gemm<K1, B1ROW, 5, false><<<256, 512, 0, stream>>>(agg1, Wpt, b1, h, nullptr, nullptr, N);

  k_agg2<<<(N + 3) / 4, 256, 0, stream>>>(h, rowptr, csr, hsum, N);

  k_gemm<HDIM, HDIM, 8, true><<<256, 512, 0, stream>>>(hsum, W2t, b2, nullptr, bids, out, N);
}